// Round 2
// baseline (422.691 us; speedup 1.0000x reference)
//
#include <hip/hip_runtime.h>

#define ROWS 131072
#define COLS 256
#define NM   128   // num masked = COLS/2

// One wave (64 lanes) per row; 4 rows per 256-thread block.
// All LDS is wave-private; __syncthreads() kept for ordering safety (cost
// is hidden by occupancy — 7 KiB LDS/block, tiny VGPR count).
__global__ __launch_bounds__(256) void masker_kernel(
    const float* __restrict__ x,
    const int*   __restrict__ sidx,
    float*       __restrict__ out)
{
    __shared__ unsigned char flags[4][256];
    __shared__ float stage[4][3 * NM];   // [mo | ud | ui] per wave
    const int wave = threadIdx.x >> 6;
    const int lane = threadIdx.x & 63;
    const long long row = (long long)blockIdx.x * 4 + wave;

    // zero this row's flag array: 64 lanes x 4 B = 256 B
    ((unsigned int*)flags[wave])[lane] = 0u;
    __syncthreads();

    // scatter first half of the permutation (the masked set): 128 ints, 2/lane
    const int2 mi = ((const int2*)(sidx + row * COLS))[lane];
    flags[wave][mi.x] = 1;
    flags[wave][mi.y] = 1;
    __syncthreads();

    // 256-bit membership mask via 4 ballots; x loaded coalesced alongside
    const float* xrow = x + row * COLS;
    const unsigned long long lt = (1ull << lane) - 1ull;
    int pre = 0;  // masked count in columns [0, 64*k)
#pragma unroll
    for (int k = 0; k < 4; ++k) {
        const int   c  = 64 * k + lane;
        const int   f  = flags[wave][c];
        const float xv = xrow[c];
        const unsigned long long b = __ballot(f != 0);
        const int mb = pre + __popcll(b & lt);   // masked cols < c
        if (f) {
            stage[wave][mb] = (float)c;          // masked_indices value
        } else {
            const int u = c - mb;                // unmasked cols < c
            stage[wave][NM + u]     = xv;        // unmasked_data
            stage[wave][2 * NM + u] = (float)c;  // unmasked_indices
        }
        pre += __popcll(b);
    }
    __syncthreads();

    // wide, fully-coalesced, divergence-free stores: 4 x (64 lanes x 8 B)
    float* md = out;                          // masked_data (zeros)
    float* mo = out + (long long)ROWS * NM;   // masked_indices
    float* ud = out + 2ll * ROWS * NM;        // unmasked_data
    float* ui = out + 3ll * ROWS * NM;        // unmasked_indices
    const long long obase = row * NM;

    const float2* sg = (const float2*)stage[wave];
    ((float2*)(md + obase))[lane] = make_float2(0.0f, 0.0f);
    ((float2*)(mo + obase))[lane] = sg[lane];
    ((float2*)(ud + obase))[lane] = sg[64 + lane];
    ((float2*)(ui + obase))[lane] = sg[128 + lane];
}

extern "C" void kernel_launch(void* const* d_in, const int* in_sizes, int n_in,
                              void* d_out, int out_size, void* d_ws, size_t ws_size,
                              hipStream_t stream) {
    const float* x    = (const float*)d_in[0];
    const int*   sidx = (const int*)d_in[1];
    float*       out  = (float*)d_out;
    masker_kernel<<<ROWS / 4, 256, 0, stream>>>(x, sidx, out);
}